// Round 1
// baseline (140.808 us; speedup 1.0000x reference)
//
#include <hip/hip_runtime.h>

#define B_DIM 8192
#define C_DIM 4096
#define NBLOCKS 2048
#define NTHREADS 256

__device__ __forceinline__ float elem_contrib(float o, float oc, float l, float mask) {
    // BCE with log clamping (matches torch BCELoss / reference)
    float log_p   = fmaxf(__logf(o), -100.0f);        // logf(0) = -inf -> clamped to -100
    float log_1mp = fmaxf(log1pf(-o), -100.0f);
    float bce = -(l * log_p + (1.0f - l) * log_1mp);
    // sharp = o>0.5 ? o + (1-o)/4 : o - o/4  ==  o>0.5 ? 0.75o+0.25 : 0.75o
    float sharp = (o > 0.5f) ? fmaf(0.75f, o, 0.25f) : 0.75f * o;
    float d1 = o  - sharp;
    float d2 = oc - sharp;
    return mask * bce + d1 * d1 + d2 * d2;
}

__global__ __launch_bounds__(NTHREADS) void semiloss_partial_kernel(
        const float* __restrict__ out,
        const float* __restrict__ cons,
        const float* __restrict__ lab,
        const int* __restrict__ source,
        float* __restrict__ partial)
{
    const long long n4 = (long long)B_DIM * C_DIM / 4;   // 8,388,608 float4s
    long long tid    = (long long)blockIdx.x * blockDim.x + threadIdx.x;
    long long stride = (long long)gridDim.x * blockDim.x;

    const float4* __restrict__ o4 = (const float4*)out;
    const float4* __restrict__ c4 = (const float4*)cons;
    const float4* __restrict__ l4 = (const float4*)lab;

    float acc = 0.0f;
    for (long long i = tid; i < n4; i += stride) {
        float4 o  = o4[i];
        float4 oc = c4[i];
        float4 l  = l4[i];
        // element index = i*4 .. i*4+3, all in the same row (C=4096 divisible by 4)
        int row = (int)(i >> 10);            // (i*4) >> 12
        int s = source[row];
        float mask = (s == 0 || s == 1) ? 1.0f : 0.0f;
        acc += elem_contrib(o.x, oc.x, l.x, mask);
        acc += elem_contrib(o.y, oc.y, l.y, mask);
        acc += elem_contrib(o.z, oc.z, l.z, mask);
        acc += elem_contrib(o.w, oc.w, l.w, mask);
    }

    // wave (64-lane) reduction
    #pragma unroll
    for (int off = 32; off > 0; off >>= 1)
        acc += __shfl_down(acc, off, 64);

    __shared__ float red[NTHREADS / 64];
    int lane = threadIdx.x & 63;
    int wave = threadIdx.x >> 6;
    if (lane == 0) red[wave] = acc;
    __syncthreads();

    if (threadIdx.x == 0) {
        float s = 0.0f;
        #pragma unroll
        for (int w = 0; w < NTHREADS / 64; ++w) s += red[w];
        partial[blockIdx.x] = s;
    }
}

__global__ __launch_bounds__(NTHREADS) void semiloss_final_kernel(
        const float* __restrict__ partial, float* __restrict__ dout)
{
    float acc = 0.0f;
    for (int i = threadIdx.x; i < NBLOCKS; i += NTHREADS)
        acc += partial[i];

    #pragma unroll
    for (int off = 32; off > 0; off >>= 1)
        acc += __shfl_down(acc, off, 64);

    __shared__ float red[NTHREADS / 64];
    int lane = threadIdx.x & 63;
    int wave = threadIdx.x >> 6;
    if (lane == 0) red[wave] = acc;
    __syncthreads();

    if (threadIdx.x == 0) {
        float s = 0.0f;
        #pragma unroll
        for (int w = 0; w < NTHREADS / 64; ++w) s += red[w];
        dout[0] = s / (float)B_DIM;
    }
}

extern "C" void kernel_launch(void* const* d_in, const int* in_sizes, int n_in,
                              void* d_out, int out_size, void* d_ws, size_t ws_size,
                              hipStream_t stream) {
    const float* out  = (const float*)d_in[0];
    const float* cons = (const float*)d_in[1];
    const float* lab  = (const float*)d_in[2];
    const int*   src  = (const int*)d_in[3];

    float* partial = (float*)d_ws;          // NBLOCKS floats of scratch
    float* dout    = (float*)d_out;

    semiloss_partial_kernel<<<NBLOCKS, NTHREADS, 0, stream>>>(out, cons, lab, src, partial);
    semiloss_final_kernel<<<1, NTHREADS, 0, stream>>>(partial, dout);
}

// Round 2
// 74.648 us; speedup vs baseline: 1.8863x; 1.8863x over previous
//
#include <hip/hip_runtime.h>

#define B_DIM 8192
#define C_DIM 4096
#define NBLOCKS 2048
#define NTHREADS 256

// log2 clamp equivalent of max(ln(x), -100):  -100/ln(2)
#define LOG2_CLAMP (-144.26950408889634f)
#define LN2 0.6931471805599453f

__global__ __launch_bounds__(NTHREADS) void semiloss_partial_kernel(
        const float* __restrict__ out,
        const float* __restrict__ cons,
        const float* __restrict__ lab,
        const int* __restrict__ source,
        float* __restrict__ partial)
{
    const unsigned n4 = (unsigned)(B_DIM) * (unsigned)(C_DIM) / 4u;  // 8,388,608
    unsigned tid    = blockIdx.x * (unsigned)blockDim.x + threadIdx.x;
    unsigned stride = gridDim.x * (unsigned)blockDim.x;

    const float4* __restrict__ o4 = (const float4*)out;
    const float4* __restrict__ c4 = (const float4*)cons;
    const float4* __restrict__ l4 = (const float4*)lab;

    float acc_b  = 0.0f;   // sum of l*log2(p) + (1-l)*log2(1-p)   (masked)
    float acc_u2 = 0.0f;   // sum of u^2,  u = o - (o>0.5)
    float acc_d2 = 0.0f;   // sum of (oc - sharp)^2

    for (unsigned i = tid; i < n4; i += stride) {
        float4 o  = o4[i];
        float4 oc = c4[i];

        // ---- sharpening / squared terms (always) ----
        {
            float s0 = (o.x > 0.5f) ? 1.0f : 0.0f;
            float u  = o.x - s0;
            float sh = fmaf(-0.25f, u, o.x);
            float d2 = oc.x - sh;
            acc_u2 = fmaf(u, u, acc_u2);
            acc_d2 = fmaf(d2, d2, acc_d2);
        }
        {
            float s0 = (o.y > 0.5f) ? 1.0f : 0.0f;
            float u  = o.y - s0;
            float sh = fmaf(-0.25f, u, o.y);
            float d2 = oc.y - sh;
            acc_u2 = fmaf(u, u, acc_u2);
            acc_d2 = fmaf(d2, d2, acc_d2);
        }
        {
            float s0 = (o.z > 0.5f) ? 1.0f : 0.0f;
            float u  = o.z - s0;
            float sh = fmaf(-0.25f, u, o.z);
            float d2 = oc.z - sh;
            acc_u2 = fmaf(u, u, acc_u2);
            acc_d2 = fmaf(d2, d2, acc_d2);
        }
        {
            float s0 = (o.w > 0.5f) ? 1.0f : 0.0f;
            float u  = o.w - s0;
            float sh = fmaf(-0.25f, u, o.w);
            float d2 = oc.w - sh;
            acc_u2 = fmaf(u, u, acc_u2);
            acc_d2 = fmaf(d2, d2, acc_d2);
        }

        // ---- BCE (only when source[row] in {0,1}; wave-uniform branch:
        //      64 consecutive float4s -> same row since 64 | 1024) ----
        unsigned row = i >> 10;                     // (i*4) >> 12
        int s = source[row];
        if ((unsigned)s <= 1u) {
            float4 l = l4[i];
            {
                float lp = fmaxf(__log2f(o.x), LOG2_CLAMP);
                float lq = fmaxf(__log2f(1.0f - o.x), LOG2_CLAMP);
                acc_b = fmaf(l.x, lp - lq, acc_b + lq);
            }
            {
                float lp = fmaxf(__log2f(o.y), LOG2_CLAMP);
                float lq = fmaxf(__log2f(1.0f - o.y), LOG2_CLAMP);
                acc_b = fmaf(l.y, lp - lq, acc_b + lq);
            }
            {
                float lp = fmaxf(__log2f(o.z), LOG2_CLAMP);
                float lq = fmaxf(__log2f(1.0f - o.z), LOG2_CLAMP);
                acc_b = fmaf(l.z, lp - lq, acc_b + lq);
            }
            {
                float lp = fmaxf(__log2f(o.w), LOG2_CLAMP);
                float lq = fmaxf(__log2f(1.0f - o.w), LOG2_CLAMP);
                acc_b = fmaf(l.w, lp - lq, acc_b + lq);
            }
        }
    }

    // combine: bce = -ln2 * acc_b ; pseudo = 0.0625*acc_u2 ; cons = acc_d2
    float acc = fmaf(-LN2, acc_b, fmaf(0.0625f, acc_u2, acc_d2));

    // wave (64-lane) reduction
    #pragma unroll
    for (int off = 32; off > 0; off >>= 1)
        acc += __shfl_down(acc, off, 64);

    __shared__ float red[NTHREADS / 64];
    int lane = threadIdx.x & 63;
    int wave = threadIdx.x >> 6;
    if (lane == 0) red[wave] = acc;
    __syncthreads();

    if (threadIdx.x == 0) {
        float s = 0.0f;
        #pragma unroll
        for (int w = 0; w < NTHREADS / 64; ++w) s += red[w];
        partial[blockIdx.x] = s;
    }
}

__global__ __launch_bounds__(NTHREADS) void semiloss_final_kernel(
        const float* __restrict__ partial, float* __restrict__ dout)
{
    float acc = 0.0f;
    for (int i = threadIdx.x; i < NBLOCKS; i += NTHREADS)
        acc += partial[i];

    #pragma unroll
    for (int off = 32; off > 0; off >>= 1)
        acc += __shfl_down(acc, off, 64);

    __shared__ float red[NTHREADS / 64];
    int lane = threadIdx.x & 63;
    int wave = threadIdx.x >> 6;
    if (lane == 0) red[wave] = acc;
    __syncthreads();

    if (threadIdx.x == 0) {
        float s = 0.0f;
        #pragma unroll
        for (int w = 0; w < NTHREADS / 64; ++w) s += red[w];
        dout[0] = s / (float)B_DIM;
    }
}

extern "C" void kernel_launch(void* const* d_in, const int* in_sizes, int n_in,
                              void* d_out, int out_size, void* d_ws, size_t ws_size,
                              hipStream_t stream) {
    const float* out  = (const float*)d_in[0];
    const float* cons = (const float*)d_in[1];
    const float* lab  = (const float*)d_in[2];
    const int*   src  = (const int*)d_in[3];

    float* partial = (float*)d_ws;          // NBLOCKS floats of scratch
    float* dout    = (float*)d_out;

    semiloss_partial_kernel<<<NBLOCKS, NTHREADS, 0, stream>>>(out, cons, lab, src, partial);
    semiloss_final_kernel<<<1, NTHREADS, 0, stream>>>(partial, dout);
}